// Round 8
// baseline (230896.118 us; speedup 1.0000x reference)
//
#include <hip/hip_runtime.h>

// Persistent diagonal-pipelined GRU. ALL weights bf16-packed in LDS (122.9 KB)
// -> phases read zero weight bytes from L2/HBM. f32 acc via v_dot2_f32_bf16.
// Transport: r0-proven pattern ([kp][b] layout, loads consumed in-iteration).
// r7 (18.6ms, steady 19.2us/step): ds_read_b128 + w-rotation decorrelation +
// 192-thread epilogue. THIS ROUND strips serial-path overhead:
//  - drop ii-rotation (w-rotation suffices), hoist sweep base pointers,
//    full unroll -> all activation loads are base+imm, zero addr VALU,
//    compiler-managed ILP (no source-level arrays -- r1-r4 lesson).
//  - h-state carried in epilogue-thread REGISTERS (phase1 reader == phase2
//    writer) -> hF global round-trip deleted from the serial path.
//  - biases/bout hoisted to registers (were L2-fetched every step).
//  - next-step x-side FMA moved before the 2nd gridbar (off critical path).
// 256 blocks x 1024 threads (16 waves), 1 block/CU; 2 grid barriers/step.

#ifndef __has_builtin
#define __has_builtin(x) 0
#endif
#if __has_builtin(__builtin_amdgcn_fdot2_f32_bf16)
#define HAS_DOT2 1
typedef __bf16 bf16x2 __attribute__((ext_vector_type(2)));
#else
#define HAS_DOT2 0
#endif

struct GruParams {
  const float* x;            // (32, 512, 128)
  const float* Wx[3][3];     // [layer][gate z,r,g]
  const float* Wh[3][3];
  const float* bias[3][3];
  const float* Wout;         // (128, 1024)
  const float* bout;         // (128)
  unsigned* hP;              // [3][512 kp][32 b] packed bf16 pairs
  unsigned* rhP;             // same layout
  float* hF;                 // unused (kept for ws layout)
  unsigned* bar;
  float* out;                // (B,S,O)
  float* outHid;             // (B,L,H)
};

// LDS dword map: 15 weight slices x 2048 dwords, Wout 512, scratch 9472 fl
#define WH0z 0
#define WH0r 2048
#define WH0g 4096
#define WH1z 6144
#define WH1r 8192
#define WH1g 10240
#define WH2z 12288
#define WH2r 14336
#define WH2g 16384
#define WX1z 18432
#define WX1r 20480
#define WX1g 22528
#define WX2z 24576
#define WX2r 26624
#define WX2g 28672
#define WOUTO 30720
#define SCRO  31232
#define LDSB ((SCRO + 8 * 1184) * 4)    // 162,816 B <= 160 KiB

extern __shared__ unsigned lds_u[];

__device__ __forceinline__ unsigned loadcu(const unsigned* p_) {
  return __hip_atomic_load(p_, __ATOMIC_RELAXED, __HIP_MEMORY_SCOPE_AGENT);
}
__device__ __forceinline__ void storecu(unsigned* p_, unsigned v) {
  __hip_atomic_store(p_, v, __ATOMIC_RELAXED, __HIP_MEMORY_SCOPE_AGENT);
}

__device__ __forceinline__ unsigned short f2bfu(float f) {   // RNE
  union { float f; unsigned u; } c; c.f = f;
  unsigned r = c.u + 0x7fffu + ((c.u >> 16) & 1u);
  return (unsigned short)(r >> 16);
}
__device__ __forceinline__ unsigned pack2(float f0, float f1) {
  return ((unsigned)f2bfu(f1) << 16) | (unsigned)f2bfu(f0);
}

// acc += dot(bf16x2(a), bf16x2(w)) in f32
__device__ __forceinline__ float d2(float acc, unsigned a, unsigned w) {
#if HAS_DOT2
  return __builtin_amdgcn_fdot2_f32_bf16(__builtin_bit_cast(bf16x2, a),
                                         __builtin_bit_cast(bf16x2, w),
                                         acc, false);
#else
  union { unsigned u; float f; } al, ah, wl, wh;
  al.u = a << 16; ah.u = a & 0xffff0000u;
  wl.u = w << 16; wh.u = w & 0xffff0000u;
  return acc + al.f * wl.f + ah.f * wh.f;
#endif
}
// acc += dot over 4 packed pairs (one uint4 weight read)
__device__ __forceinline__ float d8(float acc, unsigned a0, unsigned a1,
                                    unsigned a2, unsigned a3, const uint4 wv) {
  return d2(d2(d2(d2(acc, a0, wv.x), a1, wv.y), a2, wv.z), a3, wv.w);
}
__device__ __forceinline__ void fma4(float& acc, float o0, float o1, float o2,
                                     float o3, const float4 v) {
  acc += o0 * v.x; acc += o1 * v.y; acc += o2 * v.z; acc += o3 * v.w;
}

// Two-level barrier: 16 groups x 16 blocks, 128B-strided lines.
__device__ __forceinline__ void gridbar(unsigned* bar, unsigned phase, int bid) {
  __syncthreads();
  if (threadIdx.x == 0) {
    const int g = bid & 15;
    unsigned* grp   = bar + (g << 5);
    unsigned* root  = bar + 512;
    unsigned* go    = bar + 544;
    unsigned* grpGo = bar + 576 + (g << 5);
    const unsigned tgt = phase << 4;
    unsigned old = __hip_atomic_fetch_add(grp, 1u, __ATOMIC_RELAXED, __HIP_MEMORY_SCOPE_AGENT);
    if (old == tgt - 1u) {
      unsigned r = __hip_atomic_fetch_add(root, 1u, __ATOMIC_RELAXED, __HIP_MEMORY_SCOPE_AGENT);
      if (r == tgt - 1u)
        __hip_atomic_store(go, phase, __ATOMIC_RELAXED, __HIP_MEMORY_SCOPE_AGENT);
      while (__hip_atomic_load(go, __ATOMIC_RELAXED, __HIP_MEMORY_SCOPE_AGENT) < phase)
        __builtin_amdgcn_s_sleep(2);
      __hip_atomic_store(grpGo, phase, __ATOMIC_RELAXED, __HIP_MEMORY_SCOPE_AGENT);
    } else {
      while (__hip_atomic_load(grpGo, __ATOMIC_RELAXED, __HIP_MEMORY_SCOPE_AGENT) < phase)
        __builtin_amdgcn_s_sleep(2);
    }
  }
  __syncthreads();
}

__global__ __launch_bounds__(1024) void gruPersist(GruParams p) {
  const int tid   = threadIdx.x;
  const int bid   = blockIdx.x;
  const int wPhys = tid >> 6;              // physical wave 0..15
  const int w     = (wPhys + bid) & 15;    // rotated kp-slice assignment
  const int lane  = tid & 63;
  const int b     = lane & 31;
  const int ks    = lane >> 5;
  const int jbase = bid << 2;
  float* scratch = (float*)(lds_u + SCRO);
  float* slot    = scratch + (wPhys & 7) * 1184;  // waves wPhys, wPhys+8 pair

  // ---- one-time: convert this block's weight slices f32 -> packed bf16 ----
  for (int d = tid; d < 15 * 2048; d += 1024) {
    const int s = d >> 11, rem = d & 2047;
    const int jj = rem >> 9, kp = rem & 511;
    const float* src;
    if (s < 9)       src = p.Wh[s / 3][s % 3];
    else if (s < 12) src = p.Wx[1][s - 9];
    else             src = p.Wx[2][s - 12];
    const size_t base = (size_t)(jbase + jj) * 1024 + (size_t)(kp << 1);
    lds_u[d] = pack2(src[base], src[base + 1]);
  }
  if (bid < 128 && tid < 512) {   // Wout row `bid`
    const size_t base = (size_t)bid * 1024 + (size_t)(tid << 1);
    lds_u[WOUTO + tid] = pack2(p.Wout[base], p.Wout[base + 1]);
  }
  __syncthreads();

  unsigned* hP0 = p.hP;            unsigned* hP1 = p.hP + 16384;
  unsigned* hP2 = p.hP + 32768;
  unsigned* rq0 = p.rhP;           unsigned* rq1 = p.rhP + 16384;
  unsigned* rq2 = p.rhP + 32768;

  // hoisted sweep base: thread covers kp = (w<<5)+(i<<3)+(ks<<2)+{0..3}
  const int sboff = ((w << 5) + (ks << 2)) * 32 + b;
  const unsigned* pA0 = hP0 + sboff;
  const unsigned* pA1 = hP1 + sboff;
  const unsigned* pA2 = hP2 + sboff;
  const unsigned* pR0 = rq0 + sboff;
  const unsigned* pR1 = rq1 + sboff;
  const unsigned* pR2 = rq2 + sboff;

  // epilogue-thread persistent state (tid<192: l=tid>>6, jp, bb)
  const int el  = tid >> 6;
  const int ejp = (tid & 63) >> 5, ebb = tid & 31;
  const int ej0 = jbase + (ejp << 1);
  float hPrev[2] = {0.f, 0.f};
  float bZ[2], bR[2], bG[2];
  if (tid < 192) {
    #pragma unroll
    for (int q = 0; q < 2; ++q) {
      bZ[q] = p.bias[el][0][ej0 + q];
      bR[q] = p.bias[el][1][ej0 + q];
      bG[q] = p.bias[el][2][ej0 + q];
    }
  }
  float boutv = 0.f;
  if (bid < 128 && tid < 32) boutv = p.bout[bid];

  unsigned phase = 0;
  float myZ[2] = {0.f, 0.f}, myGx[2] = {0.f, 0.f};

  // persistent x-side partials for the upcoming step (t=0 prologue)
  float xz[4]={0,0,0,0}, xr[4]={0,0,0,0}, xg[4]={0,0,0,0};
  {
    const float* xb = p.x + ((size_t)b << 16);   // t=0
    const int k = (w << 3) + (ks << 2);
    const float4 xv = *(const float4*)(xb + k);
    #pragma unroll
    for (int jj = 0; jj < 4; ++jj) {
      const size_t row = (size_t)(jbase + jj) * 128 + k;
      fma4(xz[jj], xv.x,xv.y,xv.z,xv.w, *(const float4*)(p.Wx[0][0] + row));
      fma4(xr[jj], xv.x,xv.y,xv.z,xv.w, *(const float4*)(p.Wx[0][1] + row));
      fma4(xg[jj], xv.x,xv.y,xv.z,xv.w, *(const float4*)(p.Wx[0][2] + row));
    }
  }

  for (int m = 0; m < 514; ++m) {
    const bool act0 = (m < 512);
    const bool act1 = (m >= 1 && m <= 512);
    const bool act2 = (m >= 2 && m <= 513);
    const int t0 = m, t1 = m - 1, t2 = m - 2, th = m - 3;

    // ===================== phase 1: all A dots ============================
    float a0z[4], a0r[4], a0g[4];
    float a1z[4]={0,0,0,0}, a1r[4]={0,0,0,0}, a1g[4]={0,0,0,0};
    float a2z[4]={0,0,0,0}, a2r[4]={0,0,0,0}, a2g[4]={0,0,0,0};
    float ah = 0.f;
    #pragma unroll
    for (int jj = 0; jj < 4; ++jj) { a0z[jj]=xz[jj]; a0r[jj]=xr[jj]; a0g[jj]=xg[jj]; }

    // sweep1 over h0: l0 z/r (Wh0) + l1 z/r/g (Wx1); all loads base+imm
    #pragma unroll
    for (int i = 0; i < 4; ++i) {
      const int kp0 = (w << 5) + (i << 3) + (ks << 2);
      const unsigned a0 = loadcu(pA0 + i*256 + 0);
      const unsigned a1 = loadcu(pA0 + i*256 + 32);
      const unsigned a2 = loadcu(pA0 + i*256 + 64);
      const unsigned a3 = loadcu(pA0 + i*256 + 96);
      #pragma unroll
      for (int jj = 0; jj < 4; ++jj) {
        const int wo = (jj << 9) + kp0;
        a0z[jj] = d8(a0z[jj], a0,a1,a2,a3, *(const uint4*)(lds_u + WH0z + wo));
        a0r[jj] = d8(a0r[jj], a0,a1,a2,a3, *(const uint4*)(lds_u + WH0r + wo));
        a1z[jj] = d8(a1z[jj], a0,a1,a2,a3, *(const uint4*)(lds_u + WX1z + wo));
        a1r[jj] = d8(a1r[jj], a0,a1,a2,a3, *(const uint4*)(lds_u + WX1r + wo));
        a1g[jj] = d8(a1g[jj], a0,a1,a2,a3, *(const uint4*)(lds_u + WX1g + wo));
      }
    }

    // sweep2 over h1: l1 z/r (Wh1) + l2 z/r/g (Wx2)
    #pragma unroll
    for (int i = 0; i < 4; ++i) {
      const int kp0 = (w << 5) + (i << 3) + (ks << 2);
      const unsigned a0 = loadcu(pA1 + i*256 + 0);
      const unsigned a1 = loadcu(pA1 + i*256 + 32);
      const unsigned a2 = loadcu(pA1 + i*256 + 64);
      const unsigned a3 = loadcu(pA1 + i*256 + 96);
      #pragma unroll
      for (int jj = 0; jj < 4; ++jj) {
        const int wo = (jj << 9) + kp0;
        a1z[jj] = d8(a1z[jj], a0,a1,a2,a3, *(const uint4*)(lds_u + WH1z + wo));
        a1r[jj] = d8(a1r[jj], a0,a1,a2,a3, *(const uint4*)(lds_u + WH1r + wo));
        a2z[jj] = d8(a2z[jj], a0,a1,a2,a3, *(const uint4*)(lds_u + WX2z + wo));
        a2r[jj] = d8(a2r[jj], a0,a1,a2,a3, *(const uint4*)(lds_u + WX2r + wo));
        a2g[jj] = d8(a2g[jj], a0,a1,a2,a3, *(const uint4*)(lds_u + WX2g + wo));
      }
    }

    // sweep3 over h2: l2 z/r (Wh2) + head (bid<128: Wout row bid)
    #pragma unroll
    for (int i = 0; i < 4; ++i) {
      const int kp0 = (w << 5) + (i << 3) + (ks << 2);
      const unsigned a0 = loadcu(pA2 + i*256 + 0);
      const unsigned a1 = loadcu(pA2 + i*256 + 32);
      const unsigned a2 = loadcu(pA2 + i*256 + 64);
      const unsigned a3 = loadcu(pA2 + i*256 + 96);
      #pragma unroll
      for (int jj = 0; jj < 4; ++jj) {
        const int wo = (jj << 9) + kp0;
        a2z[jj] = d8(a2z[jj], a0,a1,a2,a3, *(const uint4*)(lds_u + WH2z + wo));
        a2r[jj] = d8(a2r[jj], a0,a1,a2,a3, *(const uint4*)(lds_u + WH2r + wo));
      }
      if (bid < 128)
        ah = d8(ah, a0,a1,a2,a3, *(const uint4*)(lds_u + WOUTO + kp0));
    }

    // combine ks halves in-wave
    #pragma unroll
    for (int jj = 0; jj < 4; ++jj) {
      a0z[jj] += __shfl_xor(a0z[jj], 32);
      a0r[jj] += __shfl_xor(a0r[jj], 32);
      a0g[jj] += __shfl_xor(a0g[jj], 32);
      a1z[jj] += __shfl_xor(a1z[jj], 32);
      a1r[jj] += __shfl_xor(a1r[jj], 32);
      a1g[jj] += __shfl_xor(a1g[jj], 32);
      a2z[jj] += __shfl_xor(a2z[jj], 32);
      a2r[jj] += __shfl_xor(a2r[jj], 32);
      a2g[jj] += __shfl_xor(a2g[jj], 32);
    }
    ah += __shfl_xor(ah, 32);

    // two-stage fold: upper physical waves deposit, lower add
    if (wPhys >= 8 && ks == 0) {
      #pragma unroll
      for (int jj = 0; jj < 4; ++jj) {
        slot[(0*4+jj)*32 + b] = a0z[jj];
        slot[(1*4+jj)*32 + b] = a0r[jj];
        slot[(2*4+jj)*32 + b] = a0g[jj];
        slot[(3*4+jj)*32 + b] = a1z[jj];
        slot[(4*4+jj)*32 + b] = a1r[jj];
        slot[(5*4+jj)*32 + b] = a1g[jj];
        slot[(6*4+jj)*32 + b] = a2z[jj];
        slot[(7*4+jj)*32 + b] = a2r[jj];
        slot[(8*4+jj)*32 + b] = a2g[jj];
      }
      slot[1152 + b] = ah;
    }
    __syncthreads();
    if (wPhys < 8 && ks == 0) {
      #pragma unroll
      for (int jj = 0; jj < 4; ++jj) {
        slot[(0*4+jj)*32 + b] += a0z[jj];
        slot[(1*4+jj)*32 + b] += a0r[jj];
        slot[(2*4+jj)*32 + b] += a0g[jj];
        slot[(3*4+jj)*32 + b] += a1z[jj];
        slot[(4*4+jj)*32 + b] += a1r[jj];
        slot[(5*4+jj)*32 + b] += a1g[jj];
        slot[(6*4+jj)*32 + b] += a2z[jj];
        slot[(7*4+jj)*32 + b] += a2r[jj];
        slot[(8*4+jj)*32 + b] += a2g[jj];
      }
      slot[1152 + b] += ah;
    }
    __syncthreads();

    // epilogue over 192 threads: wave 0->l0, wave 1->l1, wave 2->l2
    if (tid < 192) {
      float rr0 = 0.f, rr1 = 0.f;
      #pragma unroll
      for (int q = 0; q < 2; ++q) {
        const int jj = (ejp << 1) + q;
        float sz = 0.f, sr = 0.f, sg = 0.f;
        #pragma unroll
        for (int ww = 0; ww < 8; ++ww) {
          sz += scratch[ww * 1184 + ((el*3+0)*4 + jj)*32 + ebb];
          sr += scratch[ww * 1184 + ((el*3+1)*4 + jj)*32 + ebb];
          sg += scratch[ww * 1184 + ((el*3+2)*4 + jj)*32 + ebb];
        }
        const float zp = sz + bZ[q];
        const float rp = sr + bR[q];
        myGx[q] = sg + bG[q];
        myZ[q]  = 1.f / (1.f + expf(-zp));
        const float r = 1.f / (1.f + expf(-rp));
        const float rrv = r * hPrev[q];
        if (q) rr1 = rrv; else rr0 = rrv;
      }
      unsigned* rq = (el == 0) ? rq0 : (el == 1) ? rq1 : rq2;
      storecu(rq + ((bid << 1) + ejp) * 32 + ebb, pack2(rr0, rr1));
    }
    if (m >= 3 && bid < 128 && tid < 32) {
      float s = 0.f;
      #pragma unroll
      for (int ww = 0; ww < 8; ++ww) s += scratch[ww * 1184 + 1152 + tid];
      p.out[((size_t)tid << 16) + ((size_t)th << 7) + bid] = s + boutv;
    }

    ++phase; gridbar(p.bar, phase, bid);

    // ===================== phase 2: fused C ===============================
    float c0[4]={0,0,0,0}, c1[4]={0,0,0,0}, c2[4]={0,0,0,0};
    #pragma unroll
    for (int i = 0; i < 4; ++i) {
      const int kp0 = (w << 5) + (i << 3) + (ks << 2);
      const unsigned q00 = loadcu(pR0 + i*256 + 0);
      const unsigned q01 = loadcu(pR0 + i*256 + 32);
      const unsigned q02 = loadcu(pR0 + i*256 + 64);
      const unsigned q03 = loadcu(pR0 + i*256 + 96);
      const unsigned q10 = loadcu(pR1 + i*256 + 0);
      const unsigned q11 = loadcu(pR1 + i*256 + 32);
      const unsigned q12 = loadcu(pR1 + i*256 + 64);
      const unsigned q13 = loadcu(pR1 + i*256 + 96);
      const unsigned q20 = loadcu(pR2 + i*256 + 0);
      const unsigned q21 = loadcu(pR2 + i*256 + 32);
      const unsigned q22 = loadcu(pR2 + i*256 + 64);
      const unsigned q23 = loadcu(pR2 + i*256 + 96);
      #pragma unroll
      for (int jj = 0; jj < 4; ++jj) {
        const int wo = (jj << 9) + kp0;
        c0[jj] = d8(c0[jj], q00,q01,q02,q03, *(const uint4*)(lds_u + WH0g + wo));
        c1[jj] = d8(c1[jj], q10,q11,q12,q13, *(const uint4*)(lds_u + WH1g + wo));
        c2[jj] = d8(c2[jj], q20,q21,q22,q23, *(const uint4*)(lds_u + WH2g + wo));
      }
    }
    #pragma unroll
    for (int jj = 0; jj < 4; ++jj) {
      c0[jj] += __shfl_xor(c0[jj], 32);
      c1[jj] += __shfl_xor(c1[jj], 32);
      c2[jj] += __shfl_xor(c2[jj], 32);
    }
    if (wPhys >= 8 && ks == 0) {
      #pragma unroll
      for (int jj = 0; jj < 4; ++jj) {
        slot[(0*4+jj)*32 + b] = c0[jj];
        slot[(1*4+jj)*32 + b] = c1[jj];
        slot[(2*4+jj)*32 + b] = c2[jj];
      }
    }
    __syncthreads();
    if (wPhys < 8 && ks == 0) {
      #pragma unroll
      for (int jj = 0; jj < 4; ++jj) {
        slot[(0*4+jj)*32 + b] += c0[jj];
        slot[(1*4+jj)*32 + b] += c1[jj];
        slot[(2*4+jj)*32 + b] += c2[jj];
      }
    }
    __syncthreads();
    if (tid < 192) {
      const bool act = (el == 0) ? act0 : (el == 1) ? act1 : act2;
      if (act) {
        const int tl = (el == 0) ? t0 : (el == 1) ? t1 : t2;
        #pragma unroll
        for (int q = 0; q < 2; ++q) {
          const int jj = (ejp << 1) + q;
          float cv = 0.f;
          #pragma unroll
          for (int ww = 0; ww < 8; ++ww)
            cv += scratch[ww * 1184 + (el*4 + jj)*32 + ebb];
          const float g = tanhf(cv + myGx[q]);
          const float hn = myZ[q] * hPrev[q] + (1.f - myZ[q]) * g;
          hPrev[q] = hn;
          if (tl == 511) p.outHid[ebb * 3072 + el * 1024 + (ej0 + q)] = hn;
        }
        unsigned* hq = (el == 0) ? hP0 : (el == 1) ? hP1 : hP2;
        storecu(hq + ((bid << 1) + ejp) * 32 + ebb, pack2(hPrev[0], hPrev[1]));
      }
    }

    // next-step x-side (independent of the barrier; overlaps block skew)
    #pragma unroll
    for (int jj = 0; jj < 4; ++jj) { xz[jj]=0.f; xr[jj]=0.f; xg[jj]=0.f; }
    if (m + 1 < 512) {
      const float* xb = p.x + ((size_t)b << 16) + ((size_t)(m + 1) << 7);
      const int k = (w << 3) + (ks << 2);
      const float4 xv = *(const float4*)(xb + k);
      #pragma unroll
      for (int jj = 0; jj < 4; ++jj) {
        const size_t row = (size_t)(jbase + jj) * 128 + k;
        fma4(xz[jj], xv.x,xv.y,xv.z,xv.w, *(const float4*)(p.Wx[0][0] + row));
        fma4(xr[jj], xv.x,xv.y,xv.z,xv.w, *(const float4*)(p.Wx[0][1] + row));
        fma4(xg[jj], xv.x,xv.y,xv.z,xv.w, *(const float4*)(p.Wx[0][2] + row));
      }
    }

    ++phase; gridbar(p.bar, phase, bid);
  } // m

  // final head: t=511 (16 wave-partials, stride-64 scratch slots)
  float ah = 0.f;
  if (bid < 128) {
    #pragma unroll
    for (int i = 0; i < 4; ++i) {
      const int kp0 = (w << 5) + (i << 3) + (ks << 2);
      const unsigned a0 = loadcu(pA2 + i*256 + 0);
      const unsigned a1 = loadcu(pA2 + i*256 + 32);
      const unsigned a2 = loadcu(pA2 + i*256 + 64);
      const unsigned a3 = loadcu(pA2 + i*256 + 96);
      ah = d8(ah, a0,a1,a2,a3, *(const uint4*)(lds_u + WOUTO + kp0));
    }
    ah += __shfl_xor(ah, 32);
    if (ks == 0) scratch[wPhys * 64 + b] = ah;
  }
  __syncthreads();
  if (bid < 128 && tid < 32) {
    float s = 0.f;
    #pragma unroll
    for (int ww = 0; ww < 16; ++ww) s += scratch[ww * 64 + tid];
    p.out[((size_t)tid << 16) + ((size_t)511 << 7) + bid] = s + boutv;
  }
}

// Zero hP, rhP, hF, bar (ws poisoned 0xAA before every timed launch).
__global__ void initWs(unsigned* wsd) {
  const int i = blockIdx.x * 1024 + threadIdx.x;
  if (i < 198656) wsd[i] = 0u;
}

extern "C" void kernel_launch(void* const* d_in, const int* in_sizes, int n_in,
                              void* d_out, int out_size, void* d_ws, size_t ws_size,
                              hipStream_t stream)
{
  GruParams P;
  P.x = (const float*)d_in[0];
  P.Wx[0][0] = (const float*)d_in[1];  P.Wh[0][0] = (const float*)d_in[2];
  P.bias[0][0] = (const float*)d_in[3];
  P.Wx[0][1] = (const float*)d_in[4];  P.Wh[0][1] = (const float*)d_in[5];
  P.bias[0][1] = (const float*)d_in[6];
  P.Wx[0][2] = (const float*)d_in[7];  P.Wh[0][2] = (const float*)d_in[8];
  P.bias[0][2] = (const float*)d_in[9];
  for (int l = 1; l < 3; ++l) {
    const size_t off = (size_t)(l - 1) * 1048576;
    const size_t ob  = (size_t)(l - 1) * 1024;
    P.Wx[l][0] = (const float*)d_in[10] + off; P.Wh[l][0] = (const float*)d_in[11] + off;
    P.bias[l][0] = (const float*)d_in[12] + ob;
    P.Wx[l][1] = (const float*)d_in[13] + off; P.Wh[l][1] = (const float*)d_in[14] + off;
    P.bias[l][1] = (const float*)d_in[15] + ob;
    P.Wx[l][2] = (const float*)d_in[16] + off; P.Wh[l][2] = (const float*)d_in[17] + off;
    P.bias[l][2] = (const float*)d_in[18] + ob;
  }
  P.Wout = (const float*)d_in[19];
  P.bout = (const float*)d_in[20];

  char* ws = (char*)d_ws;
  P.hP  = (unsigned*)ws;                 // 3*16384 uints  = 196,608 B
  P.rhP = (unsigned*)(ws + 196608);      // 3*16384 uints  = 196,608 B
  P.hF  = (float*)(ws + 393216);         // unused (layout kept)
  P.bar = (unsigned*)(ws + 786432);      // 2048 uints
  P.out = (float*)d_out;
  P.outHid = P.out + 2097152;

  hipFuncSetAttribute(reinterpret_cast<const void*>(gruPersist),
                      hipFuncAttributeMaxDynamicSharedMemorySize, LDSB);

  initWs<<<194, 1024, 0, stream>>>((unsigned*)ws);
  gruPersist<<<256, 1024, LDSB, stream>>>(P);
}

// Round 9
// 15381.807 us; speedup vs baseline: 15.0110x; 15.0110x over previous
//
#include <hip/hip_runtime.h>

// Persistent diagonal-pipelined GRU. ALL weights bf16-packed in LDS (122.9 KB)
// -> phases read zero weight bytes from L2/HBM. f32 acc via v_dot2_f32_bf16.
// Transport: r0-proven pattern ([kp][b] layout, loads consumed in-iteration).
// REGISTER-BUDGET LAW (r0-r8, empirical): the backend budgets VGPRs for
// 2 blocks/CU regardless of hints/dynamic-LDS: 512-thread blocks -> 128
// VGPRs (stable), 1024-thread -> 64 (r7 mildly spilled, r8's +20 persistent
// regs exploded: WRITE 375GB). r6: duration is wave-count-INVARIANT, so
// THIS ROUND runs the full r7+r8 technique set on 512-thread geometry:
//  - ds_read_b128 weight reads (uint4, 4 kp/instr), w-rotation decorrelation
//  - hoisted sweep base pointers, all activation loads base+imm, unroll 2
//  - 192-thread epilogue (3 waves, l=wave); biases + h-state in REGISTERS
//  - next-step x-side FMA computed before the 2nd gridbar (off crit path)
//  - single-stage fold (8 waves -> 8 slots, ONE __syncthreads, vs r7's two)
// 256 blocks x 512 threads, 1 block/CU; 2 grid barriers per macro-step.

#ifndef __has_builtin
#define __has_builtin(x) 0
#endif
#if __has_builtin(__builtin_amdgcn_fdot2_f32_bf16)
#define HAS_DOT2 1
typedef __bf16 bf16x2 __attribute__((ext_vector_type(2)));
#else
#define HAS_DOT2 0
#endif

struct GruParams {
  const float* x;            // (32, 512, 128)
  const float* Wx[3][3];     // [layer][gate z,r,g]
  const float* Wh[3][3];
  const float* bias[3][3];
  const float* Wout;         // (128, 1024)
  const float* bout;         // (128)
  unsigned* hP;              // [3][512 kp][32 b] packed bf16 pairs
  unsigned* rhP;             // same layout
  float* hF;                 // unused (kept for ws layout)
  unsigned* bar;
  float* out;                // (B,S,O)
  float* outHid;             // (B,L,H)
};

// LDS dword map: 15 weight slices x 2048 dwords, Wout 512, scratch 9472 fl
#define WH0z 0
#define WH0r 2048
#define WH0g 4096
#define WH1z 6144
#define WH1r 8192
#define WH1g 10240
#define WH2z 12288
#define WH2r 14336
#define WH2g 16384
#define WX1z 18432
#define WX1r 20480
#define WX1g 22528
#define WX2z 24576
#define WX2r 26624
#define WX2g 28672
#define WOUTO 30720
#define SCRO  31232
#define LDSB ((SCRO + 8 * 1184) * 4)    // 162,816 B <= 160 KiB

extern __shared__ unsigned lds_u[];

__device__ __forceinline__ unsigned loadcu(const unsigned* p_) {
  return __hip_atomic_load(p_, __ATOMIC_RELAXED, __HIP_MEMORY_SCOPE_AGENT);
}
__device__ __forceinline__ void storecu(unsigned* p_, unsigned v) {
  __hip_atomic_store(p_, v, __ATOMIC_RELAXED, __HIP_MEMORY_SCOPE_AGENT);
}

__device__ __forceinline__ unsigned short f2bfu(float f) {   // RNE
  union { float f; unsigned u; } c; c.f = f;
  unsigned r = c.u + 0x7fffu + ((c.u >> 16) & 1u);
  return (unsigned short)(r >> 16);
}
__device__ __forceinline__ unsigned pack2(float f0, float f1) {
  return ((unsigned)f2bfu(f1) << 16) | (unsigned)f2bfu(f0);
}

// acc += dot(bf16x2(a), bf16x2(w)) in f32
__device__ __forceinline__ float d2(float acc, unsigned a, unsigned w) {
#if HAS_DOT2
  return __builtin_amdgcn_fdot2_f32_bf16(__builtin_bit_cast(bf16x2, a),
                                         __builtin_bit_cast(bf16x2, w),
                                         acc, false);
#else
  union { unsigned u; float f; } al, ah, wl, wh;
  al.u = a << 16; ah.u = a & 0xffff0000u;
  wl.u = w << 16; wh.u = w & 0xffff0000u;
  return acc + al.f * wl.f + ah.f * wh.f;
#endif
}
// acc += dot over 4 packed pairs (one uint4 weight read)
__device__ __forceinline__ float d8(float acc, unsigned a0, unsigned a1,
                                    unsigned a2, unsigned a3, const uint4 wv) {
  return d2(d2(d2(d2(acc, a0, wv.x), a1, wv.y), a2, wv.z), a3, wv.w);
}
__device__ __forceinline__ void fma4(float& acc, float o0, float o1, float o2,
                                     float o3, const float4 v) {
  acc += o0 * v.x; acc += o1 * v.y; acc += o2 * v.z; acc += o3 * v.w;
}

// Two-level barrier: 16 groups x 16 blocks, 128B-strided lines.
__device__ __forceinline__ void gridbar(unsigned* bar, unsigned phase, int bid) {
  __syncthreads();
  if (threadIdx.x == 0) {
    const int g = bid & 15;
    unsigned* grp   = bar + (g << 5);
    unsigned* root  = bar + 512;
    unsigned* go    = bar + 544;
    unsigned* grpGo = bar + 576 + (g << 5);
    const unsigned tgt = phase << 4;
    unsigned old = __hip_atomic_fetch_add(grp, 1u, __ATOMIC_RELAXED, __HIP_MEMORY_SCOPE_AGENT);
    if (old == tgt - 1u) {
      unsigned r = __hip_atomic_fetch_add(root, 1u, __ATOMIC_RELAXED, __HIP_MEMORY_SCOPE_AGENT);
      if (r == tgt - 1u)
        __hip_atomic_store(go, phase, __ATOMIC_RELAXED, __HIP_MEMORY_SCOPE_AGENT);
      while (__hip_atomic_load(go, __ATOMIC_RELAXED, __HIP_MEMORY_SCOPE_AGENT) < phase)
        __builtin_amdgcn_s_sleep(2);
      __hip_atomic_store(grpGo, phase, __ATOMIC_RELAXED, __HIP_MEMORY_SCOPE_AGENT);
    } else {
      while (__hip_atomic_load(grpGo, __ATOMIC_RELAXED, __HIP_MEMORY_SCOPE_AGENT) < phase)
        __builtin_amdgcn_s_sleep(2);
    }
  }
  __syncthreads();
}

__global__ __launch_bounds__(512, 2) void gruPersist(GruParams p) {
  const int tid   = threadIdx.x;
  const int bid   = blockIdx.x;
  const int wPhys = tid >> 6;              // physical wave 0..7
  const int w     = (wPhys + bid) & 7;     // rotated kp-slice assignment
  const int lane  = tid & 63;
  const int b     = lane & 31;
  const int ks    = lane >> 5;
  const int jbase = bid << 2;
  float* scratch = (float*)(lds_u + SCRO);
  float* slot    = scratch + wPhys * 1184;

  // ---- one-time: convert this block's weight slices f32 -> packed bf16 ----
  for (int d = tid; d < 15 * 2048; d += 512) {
    const int s = d >> 11, rem = d & 2047;
    const int jj = rem >> 9, kp = rem & 511;
    const float* src;
    if (s < 9)       src = p.Wh[s / 3][s % 3];
    else if (s < 12) src = p.Wx[1][s - 9];
    else             src = p.Wx[2][s - 12];
    const size_t base = (size_t)(jbase + jj) * 1024 + (size_t)(kp << 1);
    lds_u[d] = pack2(src[base], src[base + 1]);
  }
  if (bid < 128) {   // Wout row `bid`
    const size_t base = (size_t)bid * 1024 + (size_t)(tid << 1);
    lds_u[WOUTO + tid] = pack2(p.Wout[base], p.Wout[base + 1]);
  }
  __syncthreads();

  unsigned* hP0 = p.hP;            unsigned* hP1 = p.hP + 16384;
  unsigned* hP2 = p.hP + 32768;
  unsigned* rq0 = p.rhP;           unsigned* rq1 = p.rhP + 16384;
  unsigned* rq2 = p.rhP + 32768;

  // hoisted sweep base: thread covers kp = (w<<6)+(i<<3)+(ks<<2)+{0..3}
  const int sboff = ((w << 6) + (ks << 2)) * 32 + b;
  const unsigned* pA0 = hP0 + sboff;
  const unsigned* pA1 = hP1 + sboff;
  const unsigned* pA2 = hP2 + sboff;
  const unsigned* pR0 = rq0 + sboff;
  const unsigned* pR1 = rq1 + sboff;
  const unsigned* pR2 = rq2 + sboff;

  // epilogue-thread persistent state (tid<192: l=tid>>6, jp, bb)
  const int el  = tid >> 6;
  const int ejp = (tid & 63) >> 5, ebb = tid & 31;
  const int ej0 = jbase + (ejp << 1);
  float hPrev[2] = {0.f, 0.f};
  float bZ[2], bR[2], bG[2];
  if (tid < 192) {
    #pragma unroll
    for (int q = 0; q < 2; ++q) {
      bZ[q] = p.bias[el][0][ej0 + q];
      bR[q] = p.bias[el][1][ej0 + q];
      bG[q] = p.bias[el][2][ej0 + q];
    }
  }
  float boutv = 0.f;
  if (bid < 128 && tid < 32) boutv = p.bout[bid];

  unsigned phase = 0;
  float myZ[2] = {0.f, 0.f}, myGx[2] = {0.f, 0.f};

  // persistent x-side partials for the upcoming step (t=0 prologue)
  float xz[4]={0,0,0,0}, xr[4]={0,0,0,0}, xg[4]={0,0,0,0};
  {
    const float* xb = p.x + ((size_t)b << 16);   // t=0
    #pragma unroll
    for (int i = 0; i < 2; ++i) {
      const int k = (w << 4) + (i << 3) + (ks << 2);
      const float4 xv = *(const float4*)(xb + k);
      #pragma unroll
      for (int jj = 0; jj < 4; ++jj) {
        const size_t row = (size_t)(jbase + jj) * 128 + k;
        fma4(xz[jj], xv.x,xv.y,xv.z,xv.w, *(const float4*)(p.Wx[0][0] + row));
        fma4(xr[jj], xv.x,xv.y,xv.z,xv.w, *(const float4*)(p.Wx[0][1] + row));
        fma4(xg[jj], xv.x,xv.y,xv.z,xv.w, *(const float4*)(p.Wx[0][2] + row));
      }
    }
  }

  for (int m = 0; m < 514; ++m) {
    const bool act0 = (m < 512);
    const bool act1 = (m >= 1 && m <= 512);
    const bool act2 = (m >= 2 && m <= 513);
    const int t0 = m, t1 = m - 1, t2 = m - 2, th = m - 3;

    // ===================== phase 1: all A dots ============================
    float a0z[4], a0r[4], a0g[4];
    float a1z[4]={0,0,0,0}, a1r[4]={0,0,0,0}, a1g[4]={0,0,0,0};
    float a2z[4]={0,0,0,0}, a2r[4]={0,0,0,0}, a2g[4]={0,0,0,0};
    float ah = 0.f;
    #pragma unroll
    for (int jj = 0; jj < 4; ++jj) { a0z[jj]=xz[jj]; a0r[jj]=xr[jj]; a0g[jj]=xg[jj]; }

    // sweep1 over h0: l0 z/r (Wh0) + l1 z/r/g (Wx1); all loads base+imm
    #pragma unroll 2
    for (int i = 0; i < 8; ++i) {
      const int kp0 = (w << 6) + (i << 3) + (ks << 2);
      const unsigned a0 = loadcu(pA0 + i*256 + 0);
      const unsigned a1 = loadcu(pA0 + i*256 + 32);
      const unsigned a2 = loadcu(pA0 + i*256 + 64);
      const unsigned a3 = loadcu(pA0 + i*256 + 96);
      #pragma unroll
      for (int jj = 0; jj < 4; ++jj) {
        const int wo = (jj << 9) + kp0;
        a0z[jj] = d8(a0z[jj], a0,a1,a2,a3, *(const uint4*)(lds_u + WH0z + wo));
        a0r[jj] = d8(a0r[jj], a0,a1,a2,a3, *(const uint4*)(lds_u + WH0r + wo));
        a1z[jj] = d8(a1z[jj], a0,a1,a2,a3, *(const uint4*)(lds_u + WX1z + wo));
        a1r[jj] = d8(a1r[jj], a0,a1,a2,a3, *(const uint4*)(lds_u + WX1r + wo));
        a1g[jj] = d8(a1g[jj], a0,a1,a2,a3, *(const uint4*)(lds_u + WX1g + wo));
      }
    }

    // sweep2 over h1: l1 z/r (Wh1) + l2 z/r/g (Wx2)
    #pragma unroll 2
    for (int i = 0; i < 8; ++i) {
      const int kp0 = (w << 6) + (i << 3) + (ks << 2);
      const unsigned a0 = loadcu(pA1 + i*256 + 0);
      const unsigned a1 = loadcu(pA1 + i*256 + 32);
      const unsigned a2 = loadcu(pA1 + i*256 + 64);
      const unsigned a3 = loadcu(pA1 + i*256 + 96);
      #pragma unroll
      for (int jj = 0; jj < 4; ++jj) {
        const int wo = (jj << 9) + kp0;
        a1z[jj] = d8(a1z[jj], a0,a1,a2,a3, *(const uint4*)(lds_u + WH1z + wo));
        a1r[jj] = d8(a1r[jj], a0,a1,a2,a3, *(const uint4*)(lds_u + WH1r + wo));
        a2z[jj] = d8(a2z[jj], a0,a1,a2,a3, *(const uint4*)(lds_u + WX2z + wo));
        a2r[jj] = d8(a2r[jj], a0,a1,a2,a3, *(const uint4*)(lds_u + WX2r + wo));
        a2g[jj] = d8(a2g[jj], a0,a1,a2,a3, *(const uint4*)(lds_u + WX2g + wo));
      }
    }

    // sweep3 over h2: l2 z/r (Wh2) + head (bid<128: Wout row bid)
    #pragma unroll 2
    for (int i = 0; i < 8; ++i) {
      const int kp0 = (w << 6) + (i << 3) + (ks << 2);
      const unsigned a0 = loadcu(pA2 + i*256 + 0);
      const unsigned a1 = loadcu(pA2 + i*256 + 32);
      const unsigned a2 = loadcu(pA2 + i*256 + 64);
      const unsigned a3 = loadcu(pA2 + i*256 + 96);
      #pragma unroll
      for (int jj = 0; jj < 4; ++jj) {
        const int wo = (jj << 9) + kp0;
        a2z[jj] = d8(a2z[jj], a0,a1,a2,a3, *(const uint4*)(lds_u + WH2z + wo));
        a2r[jj] = d8(a2r[jj], a0,a1,a2,a3, *(const uint4*)(lds_u + WH2r + wo));
      }
      if (bid < 128)
        ah = d8(ah, a0,a1,a2,a3, *(const uint4*)(lds_u + WOUTO + kp0));
    }

    // combine ks halves in-wave
    #pragma unroll
    for (int jj = 0; jj < 4; ++jj) {
      a0z[jj] += __shfl_xor(a0z[jj], 32);
      a0r[jj] += __shfl_xor(a0r[jj], 32);
      a0g[jj] += __shfl_xor(a0g[jj], 32);
      a1z[jj] += __shfl_xor(a1z[jj], 32);
      a1r[jj] += __shfl_xor(a1r[jj], 32);
      a1g[jj] += __shfl_xor(a1g[jj], 32);
      a2z[jj] += __shfl_xor(a2z[jj], 32);
      a2r[jj] += __shfl_xor(a2r[jj], 32);
      a2g[jj] += __shfl_xor(a2g[jj], 32);
    }
    ah += __shfl_xor(ah, 32);

    // single-stage fold: each wave owns its slot
    if (ks == 0) {
      #pragma unroll
      for (int jj = 0; jj < 4; ++jj) {
        slot[(0*4+jj)*32 + b] = a0z[jj];
        slot[(1*4+jj)*32 + b] = a0r[jj];
        slot[(2*4+jj)*32 + b] = a0g[jj];
        slot[(3*4+jj)*32 + b] = a1z[jj];
        slot[(4*4+jj)*32 + b] = a1r[jj];
        slot[(5*4+jj)*32 + b] = a1g[jj];
        slot[(6*4+jj)*32 + b] = a2z[jj];
        slot[(7*4+jj)*32 + b] = a2r[jj];
        slot[(8*4+jj)*32 + b] = a2g[jj];
      }
      slot[1152 + b] = ah;
    }
    __syncthreads();

    // epilogue over 192 threads: wave 0->l0, wave 1->l1, wave 2->l2
    if (tid < 192) {
      float rr0 = 0.f, rr1 = 0.f;
      #pragma unroll
      for (int q = 0; q < 2; ++q) {
        const int jj = (ejp << 1) + q;
        float sz = 0.f, sr = 0.f, sg = 0.f;
        #pragma unroll
        for (int ww = 0; ww < 8; ++ww) {
          sz += scratch[ww * 1184 + ((el*3+0)*4 + jj)*32 + ebb];
          sr += scratch[ww * 1184 + ((el*3+1)*4 + jj)*32 + ebb];
          sg += scratch[ww * 1184 + ((el*3+2)*4 + jj)*32 + ebb];
        }
        const float zp = sz + bZ[q];
        const float rp = sr + bR[q];
        myGx[q] = sg + bG[q];
        myZ[q]  = 1.f / (1.f + expf(-zp));
        const float r = 1.f / (1.f + expf(-rp));
        const float rrv = r * hPrev[q];
        if (q) rr1 = rrv; else rr0 = rrv;
      }
      unsigned* rq = (el == 0) ? rq0 : (el == 1) ? rq1 : rq2;
      storecu(rq + ((bid << 1) + ejp) * 32 + ebb, pack2(rr0, rr1));
    }
    if (m >= 3 && bid < 128 && tid < 32) {
      float s = 0.f;
      #pragma unroll
      for (int ww = 0; ww < 8; ++ww) s += scratch[ww * 1184 + 1152 + tid];
      p.out[((size_t)tid << 16) + ((size_t)th << 7) + bid] = s + boutv;
    }

    ++phase; gridbar(p.bar, phase, bid);

    // ===================== phase 2: fused C ===============================
    float c0[4]={0,0,0,0}, c1[4]={0,0,0,0}, c2[4]={0,0,0,0};
    #pragma unroll 2
    for (int i = 0; i < 8; ++i) {
      const int kp0 = (w << 6) + (i << 3) + (ks << 2);
      const unsigned q00 = loadcu(pR0 + i*256 + 0);
      const unsigned q01 = loadcu(pR0 + i*256 + 32);
      const unsigned q02 = loadcu(pR0 + i*256 + 64);
      const unsigned q03 = loadcu(pR0 + i*256 + 96);
      const unsigned q10 = loadcu(pR1 + i*256 + 0);
      const unsigned q11 = loadcu(pR1 + i*256 + 32);
      const unsigned q12 = loadcu(pR1 + i*256 + 64);
      const unsigned q13 = loadcu(pR1 + i*256 + 96);
      const unsigned q20 = loadcu(pR2 + i*256 + 0);
      const unsigned q21 = loadcu(pR2 + i*256 + 32);
      const unsigned q22 = loadcu(pR2 + i*256 + 64);
      const unsigned q23 = loadcu(pR2 + i*256 + 96);
      #pragma unroll
      for (int jj = 0; jj < 4; ++jj) {
        const int wo = (jj << 9) + kp0;
        c0[jj] = d8(c0[jj], q00,q01,q02,q03, *(const uint4*)(lds_u + WH0g + wo));
        c1[jj] = d8(c1[jj], q10,q11,q12,q13, *(const uint4*)(lds_u + WH1g + wo));
        c2[jj] = d8(c2[jj], q20,q21,q22,q23, *(const uint4*)(lds_u + WH2g + wo));
      }
    }
    #pragma unroll
    for (int jj = 0; jj < 4; ++jj) {
      c0[jj] += __shfl_xor(c0[jj], 32);
      c1[jj] += __shfl_xor(c1[jj], 32);
      c2[jj] += __shfl_xor(c2[jj], 32);
    }
    if (ks == 0) {
      #pragma unroll
      for (int jj = 0; jj < 4; ++jj) {
        slot[(0*4+jj)*32 + b] = c0[jj];
        slot[(1*4+jj)*32 + b] = c1[jj];
        slot[(2*4+jj)*32 + b] = c2[jj];
      }
    }
    __syncthreads();
    if (tid < 192) {
      const bool act = (el == 0) ? act0 : (el == 1) ? act1 : act2;
      if (act) {
        const int tl = (el == 0) ? t0 : (el == 1) ? t1 : t2;
        #pragma unroll
        for (int q = 0; q < 2; ++q) {
          const int jj = (ejp << 1) + q;
          float cv = 0.f;
          #pragma unroll
          for (int ww = 0; ww < 8; ++ww)
            cv += scratch[ww * 1184 + (el*4 + jj)*32 + ebb];
          const float g = tanhf(cv + myGx[q]);
          const float hn = myZ[q] * hPrev[q] + (1.f - myZ[q]) * g;
          hPrev[q] = hn;
          if (tl == 511) p.outHid[ebb * 3072 + el * 1024 + (ej0 + q)] = hn;
        }
        unsigned* hq = (el == 0) ? hP0 : (el == 1) ? hP1 : hP2;
        storecu(hq + ((bid << 1) + ejp) * 32 + ebb, pack2(hPrev[0], hPrev[1]));
      }
    }

    // next-step x-side (independent of the barrier; overlaps block skew)
    #pragma unroll
    for (int jj = 0; jj < 4; ++jj) { xz[jj]=0.f; xr[jj]=0.f; xg[jj]=0.f; }
    if (m + 1 < 512) {
      const float* xb = p.x + ((size_t)b << 16) + ((size_t)(m + 1) << 7);
      #pragma unroll
      for (int i = 0; i < 2; ++i) {
        const int k = (w << 4) + (i << 3) + (ks << 2);
        const float4 xv = *(const float4*)(xb + k);
        #pragma unroll
        for (int jj = 0; jj < 4; ++jj) {
          const size_t row = (size_t)(jbase + jj) * 128 + k;
          fma4(xz[jj], xv.x,xv.y,xv.z,xv.w, *(const float4*)(p.Wx[0][0] + row));
          fma4(xr[jj], xv.x,xv.y,xv.z,xv.w, *(const float4*)(p.Wx[0][1] + row));
          fma4(xg[jj], xv.x,xv.y,xv.z,xv.w, *(const float4*)(p.Wx[0][2] + row));
        }
      }
    }

    ++phase; gridbar(p.bar, phase, bid);
  } // m

  // final head: t=511 (8 wave-partials, stride-64 scratch slots)
  float ah = 0.f;
  if (bid < 128) {
    #pragma unroll 2
    for (int i = 0; i < 8; ++i) {
      const int kp0 = (w << 6) + (i << 3) + (ks << 2);
      const unsigned a0 = loadcu(pA2 + i*256 + 0);
      const unsigned a1 = loadcu(pA2 + i*256 + 32);
      const unsigned a2 = loadcu(pA2 + i*256 + 64);
      const unsigned a3 = loadcu(pA2 + i*256 + 96);
      ah = d8(ah, a0,a1,a2,a3, *(const uint4*)(lds_u + WOUTO + kp0));
    }
    ah += __shfl_xor(ah, 32);
    if (ks == 0) scratch[wPhys * 64 + b] = ah;
  }
  __syncthreads();
  if (bid < 128 && tid < 32) {
    float s = 0.f;
    #pragma unroll
    for (int ww = 0; ww < 8; ++ww) s += scratch[ww * 64 + tid];
    p.out[((size_t)tid << 16) + ((size_t)511 << 7) + bid] = s + boutv;
  }
}

// Zero hP, rhP, hF, bar (ws poisoned 0xAA before every timed launch).
__global__ void initWs(unsigned* wsd) {
  const int i = blockIdx.x * 1024 + threadIdx.x;
  if (i < 198656) wsd[i] = 0u;
}

extern "C" void kernel_launch(void* const* d_in, const int* in_sizes, int n_in,
                              void* d_out, int out_size, void* d_ws, size_t ws_size,
                              hipStream_t stream)
{
  GruParams P;
  P.x = (const float*)d_in[0];
  P.Wx[0][0] = (const float*)d_in[1];  P.Wh[0][0] = (const float*)d_in[2];
  P.bias[0][0] = (const float*)d_in[3];
  P.Wx[0][1] = (const float*)d_in[4];  P.Wh[0][1] = (const float*)d_in[5];
  P.bias[0][1] = (const float*)d_in[6];
  P.Wx[0][2] = (const float*)d_in[7];  P.Wh[0][2] = (const float*)d_in[8];
  P.bias[0][2] = (const float*)d_in[9];
  for (int l = 1; l < 3; ++l) {
    const size_t off = (size_t)(l - 1) * 1048576;
    const size_t ob  = (size_t)(l - 1) * 1024;
    P.Wx[l][0] = (const float*)d_in[10] + off; P.Wh[l][0] = (const float*)d_in[11] + off;
    P.bias[l][0] = (const float*)d_in[12] + ob;
    P.Wx[l][1] = (const float*)d_in[13] + off; P.Wh[l][1] = (const float*)d_in[14] + off;
    P.bias[l][1] = (const float*)d_in[15] + ob;
    P.Wx[l][2] = (const float*)d_in[16] + off; P.Wh[l][2] = (const float*)d_in[17] + off;
    P.bias[l][2] = (const float*)d_in[18] + ob;
  }
  P.Wout = (const float*)d_in[19];
  P.bout = (const float*)d_in[20];

  char* ws = (char*)d_ws;
  P.hP  = (unsigned*)ws;                 // 3*16384 uints  = 196,608 B
  P.rhP = (unsigned*)(ws + 196608);      // 3*16384 uints  = 196,608 B
  P.hF  = (float*)(ws + 393216);         // unused (layout kept)
  P.bar = (unsigned*)(ws + 786432);      // 2048 uints
  P.out = (float*)d_out;
  P.outHid = P.out + 2097152;

  hipFuncSetAttribute(reinterpret_cast<const void*>(gruPersist),
                      hipFuncAttributeMaxDynamicSharedMemorySize, LDSB);

  initWs<<<194, 1024, 0, stream>>>((unsigned*)ws);
  gruPersist<<<256, 512, LDSB, stream>>>(P);
}